// Round 2
// baseline (98.703 us; speedup 1.0000x reference)
//
#include <hip/hip_runtime.h>
#include <hip/hip_bf16.h>
#include <math.h>

#define BB 2
#define FF 32
#define NN 1024
#define HH 64
#define TI 8   // i-rows per block in edge kernel

// ---------------------------------------------------------------------------
// Prep: per (b,n,h):
//   hi = sum_f emb[b,f,n]*W1[h,f]            (i-side)
//   hj = sum_f emb[b,f,n]*W1[h,F+f] + b1[h]  (j-side)
//   A  = 0.5*W2[h]*hi,  Bv = 0.5*W2[h]*hj
//   Si[b,n] = sum_h A,  Sj[b,n] = sum_h Bv   (wave reduction, h == lane)
// Then: sum_h W2_h*relu(hi+hj) = Si + Sj + sum_h sign(W2_h)*|A_h+Bv_h|
// ---------------------------------------------------------------------------
__global__ __launch_bounds__(256) void prep_kernel(
    const float* __restrict__ emb,   // (B,F,N)
    const float* __restrict__ W1,    // (H, 2F)
    const float* __restrict__ b1,    // (H)
    const float* __restrict__ W2,    // (H)
    float* __restrict__ A,           // (B,N,H)
    float* __restrict__ Bv,          // (B,N,H)
    float* __restrict__ Si,          // (B,N)
    float* __restrict__ Sj)          // (B,N)
{
    int t = blockIdx.x * 256 + threadIdx.x;   // t in [0, B*N*H)
    int h = t & (HH - 1);
    int n = (t >> 6) & (NN - 1);
    int b = t >> 16;

    const float* e = emb + (size_t)b * FF * NN + n;
    const float* w = W1 + h * (2 * FF);

    float si = 0.f, sj = 0.f;
#pragma unroll
    for (int f = 0; f < FF; ++f) {
        float ev = e[(size_t)f * NN];
        si = fmaf(ev, w[f], si);
        sj = fmaf(ev, w[FF + f], sj);
    }
    float w2h = 0.5f * W2[h];
    float a  = si * w2h;
    float bv = (sj + b1[h]) * w2h;
    A[t]  = a;
    Bv[t] = bv;

    // full-wave (64-lane) reduction over h
    float ra = a, rb = bv;
#pragma unroll
    for (int m = 32; m > 0; m >>= 1) {
        ra += __shfl_xor(ra, m);
        rb += __shfl_xor(rb, m);
    }
    if (h == 0) {
        Si[t >> 6] = ra;
        Sj[t >> 6] = rb;
    }
}

// ---------------------------------------------------------------------------
// Edge: out[b,i,j] = sigmoid(Si[b,i] + Sj[b,j] + b2 + sum_h s_h*|A[b,i,h]+Bv[b,j,h]|)
// Thread owns j (Bv row in 64 VGPRs). A-row / Si / signs are wave-uniform
// (expect s_load). Inner loop: v_add + v_fmac(sign, abs(t)) = 2 VALU per h.
// ---------------------------------------------------------------------------
__global__ __launch_bounds__(256) void edge_kernel(
    const float* __restrict__ A,     // (B,N,H)
    const float* __restrict__ Bv,    // (B,N,H)
    const float* __restrict__ Si,    // (B,N)
    const float* __restrict__ Sj,    // (B,N)
    const float* __restrict__ W2,    // (H)
    const float* __restrict__ b2,    // (1)
    float* __restrict__ out)         // (B,N,N)
{
    const int j  = blockIdx.x * 256 + threadIdx.x;
    const int i0 = blockIdx.y * TI;
    const int b  = blockIdx.z;

    // this thread's Bv row -> 64 VGPRs
    float4 br[16];
    const float4* bp = (const float4*)(Bv + ((size_t)b * NN + j) * HH);
#pragma unroll
    for (int k = 0; k < 16; ++k) br[k] = bp[k];

    // signs of W2 (wave-uniform values)
    float sg[HH];
#pragma unroll
    for (int h = 0; h < HH; ++h) sg[h] = __builtin_copysignf(1.0f, W2[h]);

    const float base = Sj[b * NN + j] + b2[0];

    const float* Ab  = A + ((size_t)b * NN + i0) * HH;
    const float* Sib = Si + b * NN + i0;
    float* op = out + ((size_t)b * NN + i0) * NN + j;

#pragma unroll
    for (int ii = 0; ii < TI; ++ii) {
        const float* ar = Ab + (size_t)ii * HH;   // wave-uniform address
        float acc0 = base + Sib[ii];
        float acc1 = 0.f, acc2 = 0.f, acc3 = 0.f;
#pragma unroll
        for (int k = 0; k < 16; ++k) {
            const float4 b4 = br[k];
            float t0 = ar[4 * k + 0] + b4.x;
            float t1 = ar[4 * k + 1] + b4.y;
            float t2 = ar[4 * k + 2] + b4.z;
            float t3 = ar[4 * k + 3] + b4.w;
            acc0 = fmaf(sg[4 * k + 0], __builtin_fabsf(t0), acc0);
            acc1 = fmaf(sg[4 * k + 1], __builtin_fabsf(t1), acc1);
            acc2 = fmaf(sg[4 * k + 2], __builtin_fabsf(t2), acc2);
            acc3 = fmaf(sg[4 * k + 3], __builtin_fabsf(t3), acc3);
        }
        float s = (acc0 + acc1) + (acc2 + acc3);
        op[(size_t)ii * NN] = 1.0f / (1.0f + __expf(-s));
    }
}

// ---------------------------------------------------------------------------
extern "C" void kernel_launch(void* const* d_in, const int* in_sizes, int n_in,
                              void* d_out, int out_size, void* d_ws, size_t ws_size,
                              hipStream_t stream) {
    // inputs: 0 adj_in (unused), 1 emb_in, 2 layer (unused), 3 W1, 4 b1, 5 W2, 6 b2
    const float* emb = (const float*)d_in[1];
    const float* W1  = (const float*)d_in[3];
    const float* b1  = (const float*)d_in[4];
    const float* W2  = (const float*)d_in[5];
    const float* b2  = (const float*)d_in[6];
    float* out = (float*)d_out;

    float* A  = (float*)d_ws;                         // B*N*H
    float* Bv = A  + (size_t)BB * NN * HH;            // B*N*H
    float* Si = Bv + (size_t)BB * NN * HH;            // B*N
    float* Sj = Si + (size_t)BB * NN;                 // B*N

    prep_kernel<<<(BB * NN * HH) / 256, 256, 0, stream>>>(emb, W1, b1, W2, A, Bv, Si, Sj);

    dim3 grid(NN / 256, NN / TI, BB);
    edge_kernel<<<grid, 256, 0, stream>>>(A, Bv, Si, Sj, W2, b2, out);
}